// Round 1
// baseline (194.299 us; speedup 1.0000x reference)
//
#include <hip/hip_runtime.h>
#include <math.h>

// Problem constants
#define B_    16
#define C_    32
#define D_    2
#define HW_   4096              // 64*64
#define NPIX  (B_ * D_ * HW_)   // 131072 pixels
#define NPAIR 528               // C*(C+1)/2

// ---------------------------------------------------------------------------
// Prep: fold weight [O=32, C=32, C=32] into symmetric pair form
//   wsym[k][o],  k indexes pairs (c,e) with e <= c, k = c(c+1)/2 + e
//   wsym = W[o,c,e] + W[o,e,c]  (off-diag),  W[o,c,c] (diag)
// ---------------------------------------------------------------------------
__global__ void prep_wsym(const float* __restrict__ w, float* __restrict__ wsym) {
    int idx = blockIdx.x * blockDim.x + threadIdx.x;
    if (idx >= NPAIR * 32) return;
    int k = idx >> 5;
    int o = idx & 31;
    // c = largest c with c(c+1)/2 <= k
    int c = (int)((sqrtf(8.0f * (float)k + 1.0f) - 1.0f) * 0.5f);
    while ((c + 1) * (c + 2) / 2 <= k) ++c;
    while (c * (c + 1) / 2 > k) --c;
    int e = k - c * (c + 1) / 2;
    const float* wo = w + o * (C_ * C_);
    float v = (c == e) ? wo[c * C_ + c] : (wo[c * C_ + e] + wo[e * C_ + c]);
    wsym[k * 32 + o] = v;
}

// ---------------------------------------------------------------------------
// Main: one thread per pixel.
//   oc[o] = sum_k wsym[k][o] * u_k,  u_k = z_c * z_e = exp(i(x_c + x_e))
//   out[o] = atan2(Im oc, Re oc) + bias[o]
// ---------------------------------------------------------------------------
#define TPB   128
#define SLICE 65   // floats per thread slice: [0..31]=cos, [32..63]=sin, +1 pad
                   // dword bank = (65*i + e) & 31 = (i+e)&31 -> 2 lanes/bank (free)

__global__ __launch_bounds__(TPB) void bilinear_kernel(
    const float* __restrict__ x,
    const float* __restrict__ wsym,
    const float* __restrict__ bias,
    float* __restrict__ out)
{
    __shared__ float lds[TPB * SLICE];   // 33,280 B

    const int t  = blockIdx.x * TPB + threadIdx.x;   // pixel id, grid sized exactly
    const int b  = t >> 13;
    const int d  = (t >> 12) & 1;
    const int hw = t & 4095;
    const int base = b * (C_ * D_ * HW_) + d * HW_ + hw;  // + c*8192 per channel

    float* sl = lds + threadIdx.x * SLICE;

    // Stage cos/sin of the 32 channel angles (coalesced global loads per c)
    for (int c = 0; c < C_; ++c) {
        float xv = x[base + c * (D_ * HW_)];
        float s, co;
        __sincosf(xv, &s, &co);
        sl[c]      = co;
        sl[c + 32] = s;
    }

    float accr[32], acci[32];
    #pragma unroll
    for (int o = 0; o < 32; ++o) { accr[o] = 0.0f; acci[o] = 0.0f; }

    int k = 0;
    for (int c = 0; c < C_; ++c) {
        const float cvc = sl[c];
        const float svc = sl[c + 32];
        for (int e = 0; e <= c; ++e) {
            const float cve = sl[e];
            const float sve = sl[e + 32];
            // u = z_c * z_e = exp(i(x_c + x_e))
            const float ur = cvc * cve - svc * sve;
            const float ui = cvc * sve + svc * cve;
            const float* __restrict__ wr = wsym + k * 32;  // uniform address -> s_load
            #pragma unroll
            for (int o = 0; o < 32; ++o) {
                accr[o] = fmaf(wr[o], ur, accr[o]);
                acci[o] = fmaf(wr[o], ui, acci[o]);
            }
            ++k;
        }
    }

    const int obase = base;  // same layout for output [B, O, D, H, W]
    #pragma unroll
    for (int o = 0; o < 32; ++o) {
        out[obase + o * (D_ * HW_)] = atan2f(acci[o], accr[o]) + bias[o];
    }
}

// ---------------------------------------------------------------------------
extern "C" void kernel_launch(void* const* d_in, const int* in_sizes, int n_in,
                              void* d_out, int out_size, void* d_ws, size_t ws_size,
                              hipStream_t stream) {
    const float* x    = (const float*)d_in[0];
    const float* w    = (const float*)d_in[1];
    const float* bias = (const float*)d_in[2];
    float* out        = (float*)d_out;
    float* wsym       = (float*)d_ws;   // needs 528*32*4 = 67,584 B

    {
        int n = NPAIR * 32;
        int tpb = 256;
        prep_wsym<<<(n + tpb - 1) / tpb, tpb, 0, stream>>>(w, wsym);
    }
    {
        int grid = NPIX / TPB;  // 1024
        bilinear_kernel<<<grid, TPB, 0, stream>>>(x, wsym, bias, out);
    }
}